// Round 1
// baseline (694.274 us; speedup 1.0000x reference)
//
#include <hip/hip_runtime.h>
#include <math.h>

// Problem constants (from reference): N=50000 nodes, E=800000 edges,
// F_IN=33, H=128, G=64 graphs. N and E are derived from in_sizes at launch.
static constexpr int F_IN = 33;
static constexpr int H    = 128;
static constexpr int GG   = 64;

// ---------------- CSR build (per call; same work every call) ----------------

__global__ void hist_kernel(const int* __restrict__ dst, int* __restrict__ cnt, int E) {
  int i = blockIdx.x * 256 + threadIdx.x;
  if (i < E) atomicAdd(&cnt[dst[i]], 1);
}

// Single-block exclusive scan over n counters -> rowptr[n+1]; also rewrites
// the counter array in place into a "cursor" (== rowptr[0..n-1]) for the
// subsequent scatter-build.
__global__ void scan_kernel(int* __restrict__ cnt_cursor, int* __restrict__ rowptr, int n) {
  __shared__ int sums[1024];
  const int t = threadIdx.x;
  const int chunk = (n + 1023) >> 10;
  int lo = t * chunk; if (lo > n) lo = n;
  int hi = lo + chunk; if (hi > n) hi = n;
  int s = 0;
  for (int i = lo; i < hi; ++i) s += cnt_cursor[i];
  sums[t] = s;
  __syncthreads();
  for (int off = 1; off < 1024; off <<= 1) {
    int vv = (t >= off) ? sums[t - off] : 0;
    __syncthreads();
    sums[t] += vv;
    __syncthreads();
  }
  int run = sums[t] - s;          // exclusive prefix of this thread's chunk
  for (int i = lo; i < hi; ++i) {
    int c = cnt_cursor[i];
    rowptr[i] = run;
    cnt_cursor[i] = run;          // cursor for build_kernel
    run += c;
  }
  if (t == 1023) rowptr[n] = sums[1023];  // total edge count
}

__global__ void build_kernel(const int* __restrict__ src, const int* __restrict__ dst,
                             int* __restrict__ cursor, int* __restrict__ srcList, int E) {
  int i = blockIdx.x * 256 + threadIdx.x;
  if (i < E) {
    int pos = atomicAdd(&cursor[dst[i]], 1);
    srcList[pos] = src[i];
  }
}

// ---------------- Aggregation: out[i] = h[i] + sum_{j in in(i)} h[j] --------

template <int F>
__global__ void gather_kernel(const float* __restrict__ h, const int* __restrict__ rowptr,
                              const int* __restrict__ srcList, float* __restrict__ out, int n) {
  const int node = blockIdx.x;
  const int f = threadIdx.x;
  if (f >= F) return;
  const int beg = rowptr[node], end = rowptr[node + 1];
  float acc = h[(size_t)node * F + f];
  int i = beg;
  // 4-wide unroll for memory-level parallelism
  for (; i + 3 < end; i += 4) {
    int s0 = srcList[i], s1 = srcList[i + 1], s2 = srcList[i + 2], s3 = srcList[i + 3];
    float v0 = h[(size_t)s0 * F + f];
    float v1 = h[(size_t)s1 * F + f];
    float v2 = h[(size_t)s2 * F + f];
    float v3 = h[(size_t)s3 * F + f];
    acc += (v0 + v1) + (v2 + v3);
  }
  for (; i < end; ++i) acc += h[(size_t)srcList[i] * F + f];
  out[(size_t)node * F + f] = acc;
}

// ---------------- Fused GEMM (+bias, +BN, +ReLU, +segment-pool) -------------
// C[n x 128] = A[n x K] @ W[K x 128]; 64 rows x 128 cols per block,
// 256 threads, 8x4 register micro-tile per thread.

template <int K, bool BN, bool POOL, bool STORE>
__global__ __launch_bounds__(256) void mlp_gemm(
    const float* __restrict__ A, const float* __restrict__ W,
    const float* __restrict__ bias,
    const float* __restrict__ gam, const float* __restrict__ bet,
    const float* __restrict__ mu,  const float* __restrict__ var,
    float* __restrict__ out, const int* __restrict__ batch,
    float* __restrict__ pool, int n) {
  __shared__ float As[64 * K];
  const int tx = threadIdx.x;
  const long rowBase = (long)blockIdx.x * 64;
  const long nK = (long)n * K;

  // Stage A tile (rows are contiguous, so the tile is one flat span).
  if constexpr ((K & 3) == 0) {
    for (int i = tx; i < 64 * K / 4; i += 256) {
      long gflat = rowBase * K + (long)i * 4;
      float4 val = make_float4(0.f, 0.f, 0.f, 0.f);
      if (gflat < nK) val = *(const float4*)(A + gflat);
      ((float4*)As)[i] = val;
    }
  } else {
    for (int i = tx; i < 64 * K; i += 256) {
      long gflat = rowBase * K + i;
      As[i] = (gflat < nK) ? A[gflat] : 0.f;
    }
  }
  __syncthreads();

  const int cg = (tx & 31) * 4;   // column base (0..124)
  const int rg = (tx >> 5) * 8;   // row base within tile (0..56)

  float acc[8][4];
#pragma unroll
  for (int i = 0; i < 8; ++i)
    for (int j = 0; j < 4; ++j) acc[i][j] = 0.f;

#pragma unroll 4
  for (int k = 0; k < K; ++k) {
    const float4 w4 = *(const float4*)(W + k * H + cg);
#pragma unroll
    for (int i = 0; i < 8; ++i) {
      const float a = As[(rg + i) * K + k];
      acc[i][0] = fmaf(a, w4.x, acc[i][0]);
      acc[i][1] = fmaf(a, w4.y, acc[i][1]);
      acc[i][2] = fmaf(a, w4.z, acc[i][2]);
      acc[i][3] = fmaf(a, w4.w, acc[i][3]);
    }
  }

  const float4 b4 = *(const float4*)(bias + cg);
  float sc[4], sh[4];
  if constexpr (BN) {
#pragma unroll
    for (int j = 0; j < 4; ++j) {
      float s = gam[cg + j] * rsqrtf(var[cg + j] + 1e-5f);
      sc[j] = s;
      sh[j] = bet[cg + j] - mu[cg + j] * s;
    }
  }

  int gcur = -1;
  float ps[4] = {0.f, 0.f, 0.f, 0.f};
#pragma unroll
  for (int i = 0; i < 8; ++i) {
    long row = rowBase + rg + i;
    if (row >= n) break;
    float vv[4] = {acc[i][0] + b4.x, acc[i][1] + b4.y,
                   acc[i][2] + b4.z, acc[i][3] + b4.w};
#pragma unroll
    for (int j = 0; j < 4; ++j) {
      if constexpr (BN) vv[j] = fmaf(vv[j], sc[j], sh[j]);
      vv[j] = vv[j] > 0.f ? vv[j] : 0.f;
    }
    if constexpr (STORE) {
      float4 o; o.x = vv[0]; o.y = vv[1]; o.z = vv[2]; o.w = vv[3];
      *(float4*)(out + row * H + cg) = o;
    }
    if constexpr (POOL) {
      // batch is sorted -> run-length accumulate, flush on graph change.
      int gb = batch[row];
      if (gb != gcur) {
        if (gcur >= 0) {
#pragma unroll
          for (int j = 0; j < 4; ++j) atomicAdd(pool + gcur * H + cg + j, ps[j]);
        }
        gcur = gb;
        ps[0] = vv[0]; ps[1] = vv[1]; ps[2] = vv[2]; ps[3] = vv[3];
      } else {
        ps[0] += vv[0]; ps[1] += vv[1]; ps[2] += vv[2]; ps[3] += vv[3];
      }
    }
  }
  if constexpr (POOL) {
    if (gcur >= 0) {
#pragma unroll
      for (int j = 0; j < 4; ++j) atomicAdd(pool + gcur * H + cg + j, ps[j]);
    }
  }
}

// ---------------- Head MLP: [G,384] -> 50 -> 20 -> 1 -> sigmoid -------------

__global__ void head_kernel(const float* __restrict__ pools,
                            const float* __restrict__ l1w, const float* __restrict__ l1b,
                            const float* __restrict__ l2w, const float* __restrict__ l2b,
                            const float* __restrict__ l3w, const float* __restrict__ l3b,
                            float* __restrict__ out) {
  const int g = blockIdx.x;
  const int t = threadIdx.x;  // 64 threads
  __shared__ float hin[3 * H];
  __shared__ float t1[50];
  __shared__ float t2[20];
  for (int idx = t; idx < 3 * H; idx += 64) {
    int l = idx >> 7, f = idx & 127;
    hin[idx] = pools[(size_t)l * GG * H + (size_t)g * H + f];
  }
  __syncthreads();
  if (t < 50) {
    float s = l1b[t];
    for (int k = 0; k < 3 * H; ++k) s = fmaf(hin[k], l1w[k * 50 + t], s);
    t1[t] = s > 0.f ? s : 0.f;
  }
  __syncthreads();
  if (t < 20) {
    float s = l2b[t];
    for (int k = 0; k < 50; ++k) s = fmaf(t1[k], l2w[k * 20 + t], s);
    t2[t] = s > 0.f ? s : 0.f;
  }
  __syncthreads();
  if (t == 0) {
    float s = l3b[0];
    for (int k = 0; k < 20; ++k) s = fmaf(t2[k], l3w[k], s);
    out[g] = 1.f / (1.f + expf(-s));
  }
}

// ---------------- launch ----------------------------------------------------

extern "C" void kernel_launch(void* const* d_in, const int* in_sizes, int n_in,
                              void* d_out, int out_size, void* d_ws, size_t ws_size,
                              hipStream_t stream) {
  const float* x    = (const float*)d_in[0];
  const int* ei     = (const int*)d_in[1];
  const int* batch  = (const int*)d_in[2];
  const int N = in_sizes[2];
  const int E = in_sizes[1] / 2;
  const int* src = ei;
  const int* dst = ei + E;

  // per-layer params: base index 3 + 8*layer
  const float* w1[3]; const float* b1[3]; const float* gm[3]; const float* be[3];
  const float* mu[3]; const float* vr[3]; const float* w2[3]; const float* b2[3];
  for (int l = 0; l < 3; ++l) {
    int b = 3 + 8 * l;
    w1[l] = (const float*)d_in[b + 0];
    b1[l] = (const float*)d_in[b + 1];
    gm[l] = (const float*)d_in[b + 2];
    be[l] = (const float*)d_in[b + 3];
    mu[l] = (const float*)d_in[b + 4];
    vr[l] = (const float*)d_in[b + 5];
    w2[l] = (const float*)d_in[b + 6];
    b2[l] = (const float*)d_in[b + 7];
  }
  const float* l1w = (const float*)d_in[27];
  const float* l1b = (const float*)d_in[28];
  const float* l2w = (const float*)d_in[29];
  const float* l2b = (const float*)d_in[30];
  const float* l3w = (const float*)d_in[31];
  const float* l3b = (const float*)d_in[32];

  // workspace carve-up
  char* ws = (char*)d_ws;
  size_t off = 0;
  auto take = [&](size_t bytes) {
    size_t p = off;
    off += (bytes + 255) & ~(size_t)255;
    return p;
  };
  float* A      = (float*)(ws + take((size_t)N * H * 4));   // agg result (layer1 uses [N,33])
  float* Z      = (float*)(ws + take((size_t)N * H * 4));   // post-BN-ReLU intermediate
  float* P      = (float*)(ws + take((size_t)N * H * 4));   // layer output h
  float* pools  = (float*)(ws + take((size_t)3 * GG * H * 4));
  int* rowptr   = (int*)(ws + take((size_t)(N + 1) * 4));
  int* cursor   = (int*)(ws + take((size_t)N * 4));
  int* srcList  = (int*)(ws + take((size_t)E * 4));
  (void)ws_size; (void)n_in; (void)out_size;

  const int eb = (E + 255) / 256;
  const int gb = (N + 63) / 64;

  // zero counters + pools (ws is poisoned 0xAA before every call)
  hipMemsetAsync(cursor, 0, (size_t)N * 4, stream);
  hipMemsetAsync(pools, 0, (size_t)3 * GG * H * 4, stream);

  // CSR by dst
  hist_kernel<<<eb, 256, 0, stream>>>(dst, cursor, E);
  scan_kernel<<<1, 1024, 0, stream>>>(cursor, rowptr, N);
  build_kernel<<<eb, 256, 0, stream>>>(src, dst, cursor, srcList, E);

  // ---- layer 1 (K = 33) ----
  gather_kernel<F_IN><<<N, 64, 0, stream>>>(x, rowptr, srcList, A, N);
  mlp_gemm<F_IN, true, false, true><<<gb, 256, 0, stream>>>(
      A, w1[0], b1[0], gm[0], be[0], mu[0], vr[0], Z, nullptr, nullptr, N);
  mlp_gemm<H, false, true, true><<<gb, 256, 0, stream>>>(
      Z, w2[0], b2[0], nullptr, nullptr, nullptr, nullptr, P, batch, pools, N);

  // ---- layer 2 ----
  gather_kernel<H><<<N, H, 0, stream>>>(P, rowptr, srcList, A, N);
  mlp_gemm<H, true, false, true><<<gb, 256, 0, stream>>>(
      A, w1[1], b1[1], gm[1], be[1], mu[1], vr[1], Z, nullptr, nullptr, N);
  mlp_gemm<H, false, true, true><<<gb, 256, 0, stream>>>(
      Z, w2[1], b2[1], nullptr, nullptr, nullptr, nullptr, P, batch, pools + GG * H, N);

  // ---- layer 3 (h3 never materialized; pooled only) ----
  gather_kernel<H><<<N, H, 0, stream>>>(P, rowptr, srcList, A, N);
  mlp_gemm<H, true, false, true><<<gb, 256, 0, stream>>>(
      A, w1[2], b1[2], gm[2], be[2], mu[2], vr[2], Z, nullptr, nullptr, N);
  mlp_gemm<H, false, true, false><<<gb, 256, 0, stream>>>(
      Z, w2[2], b2[2], nullptr, nullptr, nullptr, nullptr, nullptr, batch, pools + 2 * GG * H, N);

  // ---- head ----
  head_kernel<<<GG, 64, 0, stream>>>(pools, l1w, l1b, l2w, l2b, l3w, l3b, (float*)d_out);
}

// Round 2
// 596.940 us; speedup vs baseline: 1.1631x; 1.1631x over previous
//
#include <hip/hip_runtime.h>
#include <math.h>

// Problem constants (from reference): N=50000 nodes, E=800000 edges,
// F_IN=33, H=128, G=64 graphs. N and E are derived from in_sizes at launch.
static constexpr int F_IN = 33;
static constexpr int H    = 128;
static constexpr int GG   = 64;

// ---------------- CSR build (per call; same work every call) ----------------

__global__ void hist_kernel(const int* __restrict__ dst, int* __restrict__ cnt, int E) {
  int i = blockIdx.x * 256 + threadIdx.x;
  if (i < E) atomicAdd(&cnt[dst[i]], 1);
}

// Hierarchical exclusive scan over n counters (1024 elements per block).
// Stage 1: per-block sums.
__global__ void block_reduce(const int* __restrict__ cnt, int* __restrict__ partial, int n) {
  __shared__ int s[256];
  const int t = threadIdx.x;
  const int base = blockIdx.x * 1024;
  int sum = 0;
  for (int i = t; i < 1024; i += 256) {
    int idx = base + i;
    if (idx < n) sum += cnt[idx];
  }
  s[t] = sum;
  __syncthreads();
  for (int off = 128; off > 0; off >>= 1) {
    if (t < off) s[t] += s[t + off];
    __syncthreads();
  }
  if (t == 0) partial[blockIdx.x] = s[0];
}

// Stage 2: single small block scans the (few dozen) partials in place
// (inclusive -> exclusive) and writes the grand total to rowptr[n].
__global__ void scan_partials(int* __restrict__ partial, int nb, int* __restrict__ total_out) {
  __shared__ int s[256];
  const int t = threadIdx.x;
  int carry = 0;
  for (int base = 0; base < nb; base += 256) {
    int v = (base + t < nb) ? partial[base + t] : 0;
    s[t] = v;
    __syncthreads();
    for (int off = 1; off < 256; off <<= 1) {
      int add = (t >= off) ? s[t - off] : 0;
      __syncthreads();
      s[t] += add;
      __syncthreads();
    }
    if (base + t < nb) partial[base + t] = s[t] - v + carry;
    carry += s[255];
    __syncthreads();
  }
  if (t == 0) *total_out = carry;
}

// Stage 3: per-block exclusive scan (4 consecutive counters per thread) + add
// block offset; writes rowptr and rewrites cnt in place as the build cursor.
__global__ void block_scan(int* __restrict__ cnt_cursor, const int* __restrict__ partial,
                           int* __restrict__ rowptr, int n) {
  __shared__ int s[256];
  const int t = threadIdx.x;
  const int base = blockIdx.x * 1024;
  int v[4];
  int sum = 0;
#pragma unroll
  for (int j = 0; j < 4; ++j) {
    int idx = base + t * 4 + j;
    v[j] = (idx < n) ? cnt_cursor[idx] : 0;
    sum += v[j];
  }
  s[t] = sum;
  __syncthreads();
  for (int off = 1; off < 256; off <<= 1) {
    int add = (t >= off) ? s[t - off] : 0;
    __syncthreads();
    s[t] += add;
    __syncthreads();
  }
  int excl = s[t] - sum + partial[blockIdx.x];
#pragma unroll
  for (int j = 0; j < 4; ++j) {
    int idx = base + t * 4 + j;
    if (idx < n) {
      rowptr[idx] = excl;
      cnt_cursor[idx] = excl;
    }
    excl += v[j];
  }
}

__global__ void build_kernel(const int* __restrict__ src, const int* __restrict__ dst,
                             int* __restrict__ cursor, int* __restrict__ srcList, int E) {
  int i = blockIdx.x * 256 + threadIdx.x;
  if (i < E) {
    int pos = atomicAdd(&cursor[dst[i]], 1);
    srcList[pos] = src[i];
  }
}

// ---------------- Aggregation: out[i] = h[i] + sum_{j in in(i)} h[j] --------

template <int F>
__global__ void gather_kernel(const float* __restrict__ h, const int* __restrict__ rowptr,
                              const int* __restrict__ srcList, float* __restrict__ out, int n) {
  const int node = blockIdx.x;
  const int f = threadIdx.x;
  if (f >= F) return;
  const int beg = rowptr[node], end = rowptr[node + 1];
  float acc = h[(size_t)node * F + f];
  int i = beg;
  // 4-wide unroll for memory-level parallelism
  for (; i + 3 < end; i += 4) {
    int s0 = srcList[i], s1 = srcList[i + 1], s2 = srcList[i + 2], s3 = srcList[i + 3];
    float v0 = h[(size_t)s0 * F + f];
    float v1 = h[(size_t)s1 * F + f];
    float v2 = h[(size_t)s2 * F + f];
    float v3 = h[(size_t)s3 * F + f];
    acc += (v0 + v1) + (v2 + v3);
  }
  for (; i < end; ++i) acc += h[(size_t)srcList[i] * F + f];
  out[(size_t)node * F + f] = acc;
}

// ---------------- Fused GEMM (+bias, +BN, +ReLU, +segment-pool) -------------
// C[n x 128] = A[n x K] @ W[K x 128]; 64 rows x 128 cols per block,
// 256 threads, 8x4 register micro-tile per thread.

template <int K, bool BN, bool POOL, bool STORE>
__global__ __launch_bounds__(256) void mlp_gemm(
    const float* __restrict__ A, const float* __restrict__ W,
    const float* __restrict__ bias,
    const float* __restrict__ gam, const float* __restrict__ bet,
    const float* __restrict__ mu,  const float* __restrict__ var,
    float* __restrict__ out, const int* __restrict__ batch,
    float* __restrict__ pool, int n) {
  __shared__ float As[64 * K];
  const int tx = threadIdx.x;
  const long rowBase = (long)blockIdx.x * 64;
  const long nK = (long)n * K;

  // Stage A tile (rows are contiguous, so the tile is one flat span).
  if constexpr ((K & 3) == 0) {
    for (int i = tx; i < 64 * K / 4; i += 256) {
      long gflat = rowBase * K + (long)i * 4;
      float4 val = make_float4(0.f, 0.f, 0.f, 0.f);
      if (gflat < nK) val = *(const float4*)(A + gflat);
      ((float4*)As)[i] = val;
    }
  } else {
    for (int i = tx; i < 64 * K; i += 256) {
      long gflat = rowBase * K + i;
      As[i] = (gflat < nK) ? A[gflat] : 0.f;
    }
  }
  __syncthreads();

  const int cg = (tx & 31) * 4;   // column base (0..124)
  const int rg = (tx >> 5) * 8;   // row base within tile (0..56)

  float acc[8][4];
#pragma unroll
  for (int i = 0; i < 8; ++i)
    for (int j = 0; j < 4; ++j) acc[i][j] = 0.f;

#pragma unroll 4
  for (int k = 0; k < K; ++k) {
    const float4 w4 = *(const float4*)(W + k * H + cg);
#pragma unroll
    for (int i = 0; i < 8; ++i) {
      const float a = As[(rg + i) * K + k];
      acc[i][0] = fmaf(a, w4.x, acc[i][0]);
      acc[i][1] = fmaf(a, w4.y, acc[i][1]);
      acc[i][2] = fmaf(a, w4.z, acc[i][2]);
      acc[i][3] = fmaf(a, w4.w, acc[i][3]);
    }
  }

  const float4 b4 = *(const float4*)(bias + cg);
  float sc[4], sh[4];
  if constexpr (BN) {
#pragma unroll
    for (int j = 0; j < 4; ++j) {
      float s = gam[cg + j] * rsqrtf(var[cg + j] + 1e-5f);
      sc[j] = s;
      sh[j] = bet[cg + j] - mu[cg + j] * s;
    }
  }

  int gcur = -1;
  float ps[4] = {0.f, 0.f, 0.f, 0.f};
#pragma unroll
  for (int i = 0; i < 8; ++i) {
    long row = rowBase + rg + i;
    if (row >= n) break;
    float vv[4] = {acc[i][0] + b4.x, acc[i][1] + b4.y,
                   acc[i][2] + b4.z, acc[i][3] + b4.w};
#pragma unroll
    for (int j = 0; j < 4; ++j) {
      if constexpr (BN) vv[j] = fmaf(vv[j], sc[j], sh[j]);
      vv[j] = vv[j] > 0.f ? vv[j] : 0.f;
    }
    if constexpr (STORE) {
      float4 o; o.x = vv[0]; o.y = vv[1]; o.z = vv[2]; o.w = vv[3];
      *(float4*)(out + row * H + cg) = o;
    }
    if constexpr (POOL) {
      // batch is sorted -> run-length accumulate, flush on graph change.
      int gb = batch[row];
      if (gb != gcur) {
        if (gcur >= 0) {
#pragma unroll
          for (int j = 0; j < 4; ++j) atomicAdd(pool + gcur * H + cg + j, ps[j]);
        }
        gcur = gb;
        ps[0] = vv[0]; ps[1] = vv[1]; ps[2] = vv[2]; ps[3] = vv[3];
      } else {
        ps[0] += vv[0]; ps[1] += vv[1]; ps[2] += vv[2]; ps[3] += vv[3];
      }
    }
  }
  if constexpr (POOL) {
    if (gcur >= 0) {
#pragma unroll
      for (int j = 0; j < 4; ++j) atomicAdd(pool + gcur * H + cg + j, ps[j]);
    }
  }
}

// ---------------- Head MLP: [G,384] -> 50 -> 20 -> 1 -> sigmoid -------------

__global__ void head_kernel(const float* __restrict__ pools,
                            const float* __restrict__ l1w, const float* __restrict__ l1b,
                            const float* __restrict__ l2w, const float* __restrict__ l2b,
                            const float* __restrict__ l3w, const float* __restrict__ l3b,
                            float* __restrict__ out) {
  const int g = blockIdx.x;
  const int t = threadIdx.x;  // 64 threads
  __shared__ float hin[3 * H];
  __shared__ float t1[50];
  __shared__ float t2[20];
  for (int idx = t; idx < 3 * H; idx += 64) {
    int l = idx >> 7, f = idx & 127;
    hin[idx] = pools[(size_t)l * GG * H + (size_t)g * H + f];
  }
  __syncthreads();
  if (t < 50) {
    float s = l1b[t];
    for (int k = 0; k < 3 * H; ++k) s = fmaf(hin[k], l1w[k * 50 + t], s);
    t1[t] = s > 0.f ? s : 0.f;
  }
  __syncthreads();
  if (t < 20) {
    float s = l2b[t];
    for (int k = 0; k < 50; ++k) s = fmaf(t1[k], l2w[k * 20 + t], s);
    t2[t] = s > 0.f ? s : 0.f;
  }
  __syncthreads();
  if (t == 0) {
    float s = l3b[0];
    for (int k = 0; k < 20; ++k) s = fmaf(t2[k], l3w[k], s);
    out[g] = 1.f / (1.f + expf(-s));
  }
}

// ---------------- launch ----------------------------------------------------

extern "C" void kernel_launch(void* const* d_in, const int* in_sizes, int n_in,
                              void* d_out, int out_size, void* d_ws, size_t ws_size,
                              hipStream_t stream) {
  const float* x    = (const float*)d_in[0];
  const int* ei     = (const int*)d_in[1];
  const int* batch  = (const int*)d_in[2];
  const int N = in_sizes[2];
  const int E = in_sizes[1] / 2;
  const int* src = ei;
  const int* dst = ei + E;

  // per-layer params: base index 3 + 8*layer
  const float* w1[3]; const float* b1[3]; const float* gm[3]; const float* be[3];
  const float* mu[3]; const float* vr[3]; const float* w2[3]; const float* b2[3];
  for (int l = 0; l < 3; ++l) {
    int b = 3 + 8 * l;
    w1[l] = (const float*)d_in[b + 0];
    b1[l] = (const float*)d_in[b + 1];
    gm[l] = (const float*)d_in[b + 2];
    be[l] = (const float*)d_in[b + 3];
    mu[l] = (const float*)d_in[b + 4];
    vr[l] = (const float*)d_in[b + 5];
    w2[l] = (const float*)d_in[b + 6];
    b2[l] = (const float*)d_in[b + 7];
  }
  const float* l1w = (const float*)d_in[27];
  const float* l1b = (const float*)d_in[28];
  const float* l2w = (const float*)d_in[29];
  const float* l2b = (const float*)d_in[30];
  const float* l3w = (const float*)d_in[31];
  const float* l3b = (const float*)d_in[32];

  // workspace carve-up
  char* ws = (char*)d_ws;
  size_t off = 0;
  auto take = [&](size_t bytes) {
    size_t p = off;
    off += (bytes + 255) & ~(size_t)255;
    return p;
  };
  float* A      = (float*)(ws + take((size_t)N * H * 4));   // agg result (layer1 uses [N,33])
  float* Z      = (float*)(ws + take((size_t)N * H * 4));   // post-BN-ReLU intermediate
  float* P      = (float*)(ws + take((size_t)N * H * 4));   // layer output h
  float* pools  = (float*)(ws + take((size_t)3 * GG * H * 4));
  int* rowptr   = (int*)(ws + take((size_t)(N + 1) * 4));
  int* cursor   = (int*)(ws + take((size_t)N * 4));
  int* srcList  = (int*)(ws + take((size_t)E * 4));
  int* partial  = (int*)(ws + take((size_t)1024 * 4));
  (void)ws_size; (void)n_in; (void)out_size;

  const int eb = (E + 255) / 256;
  const int gb = (N + 63) / 64;
  const int nb = (N + 1023) / 1024;   // scan blocks (1024 counters each)

  // zero counters + pools (ws is poisoned 0xAA before every call)
  hipMemsetAsync(cursor, 0, (size_t)N * 4, stream);
  hipMemsetAsync(pools, 0, (size_t)3 * GG * H * 4, stream);

  // CSR by dst (hierarchical scan: reduce -> scan partials -> block scan)
  hist_kernel<<<eb, 256, 0, stream>>>(dst, cursor, E);
  block_reduce<<<nb, 256, 0, stream>>>(cursor, partial, N);
  scan_partials<<<1, 256, 0, stream>>>(partial, nb, rowptr + N);
  block_scan<<<nb, 256, 0, stream>>>(cursor, partial, rowptr, N);
  build_kernel<<<eb, 256, 0, stream>>>(src, dst, cursor, srcList, E);

  // ---- layer 1 (K = 33) ----
  gather_kernel<F_IN><<<N, 64, 0, stream>>>(x, rowptr, srcList, A, N);
  mlp_gemm<F_IN, true, false, true><<<gb, 256, 0, stream>>>(
      A, w1[0], b1[0], gm[0], be[0], mu[0], vr[0], Z, nullptr, nullptr, N);
  mlp_gemm<H, false, true, true><<<gb, 256, 0, stream>>>(
      Z, w2[0], b2[0], nullptr, nullptr, nullptr, nullptr, P, batch, pools, N);

  // ---- layer 2 ----
  gather_kernel<H><<<N, H, 0, stream>>>(P, rowptr, srcList, A, N);
  mlp_gemm<H, true, false, true><<<gb, 256, 0, stream>>>(
      A, w1[1], b1[1], gm[1], be[1], mu[1], vr[1], Z, nullptr, nullptr, N);
  mlp_gemm<H, false, true, true><<<gb, 256, 0, stream>>>(
      Z, w2[1], b2[1], nullptr, nullptr, nullptr, nullptr, P, batch, pools + GG * H, N);

  // ---- layer 3 (h3 never materialized; pooled only) ----
  gather_kernel<H><<<N, H, 0, stream>>>(P, rowptr, srcList, A, N);
  mlp_gemm<H, true, false, true><<<gb, 256, 0, stream>>>(
      A, w1[2], b1[2], gm[2], be[2], mu[2], vr[2], Z, nullptr, nullptr, N);
  mlp_gemm<H, false, true, false><<<gb, 256, 0, stream>>>(
      Z, w2[2], b2[2], nullptr, nullptr, nullptr, nullptr, nullptr, batch, pools + 2 * GG * H, N);

  // ---- head ----
  head_kernel<<<GG, 64, 0, stream>>>(pools, l1w, l1b, l2w, l2b, l3w, l3b, (float*)d_out);
}

// Round 3
// 525.790 us; speedup vs baseline: 1.3204x; 1.1353x over previous
//
#include <hip/hip_runtime.h>
#include <math.h>

// N=50000 nodes, E=800000 edges, F_IN=33, H=128, G=64 graphs.
static constexpr int F_IN = 33;
static constexpr int H    = 128;
static constexpr int GG   = 64;

typedef __attribute__((ext_vector_type(8))) short short8;
typedef __attribute__((ext_vector_type(4))) float f32x4;

__device__ __forceinline__ unsigned short f2bf(float f) {
  union { float f; unsigned u; } v; v.f = f;
  unsigned r = v.u + 0x7fffu + ((v.u >> 16) & 1u);   // RNE
  return (unsigned short)(r >> 16);
}
__device__ __forceinline__ float bf2f(unsigned short b) {
  union { unsigned u; float f; } v; v.u = ((unsigned)b) << 16;
  return v.f;
}

// ---------------- CSR build ----------------

__global__ void hist_kernel(const int* __restrict__ dst, int* __restrict__ cnt, int E) {
  int i = blockIdx.x * 256 + threadIdx.x;
  if (i < E) atomicAdd(&cnt[dst[i]], 1);
}

__global__ void block_reduce(const int* __restrict__ cnt, int* __restrict__ partial, int n) {
  __shared__ int s[256];
  const int t = threadIdx.x;
  const int base = blockIdx.x * 1024;
  int sum = 0;
  for (int i = t; i < 1024; i += 256) {
    int idx = base + i;
    if (idx < n) sum += cnt[idx];
  }
  s[t] = sum;
  __syncthreads();
  for (int off = 128; off > 0; off >>= 1) {
    if (t < off) s[t] += s[t + off];
    __syncthreads();
  }
  if (t == 0) partial[blockIdx.x] = s[0];
}

__global__ void scan_partials(int* __restrict__ partial, int nb, int* __restrict__ total_out) {
  __shared__ int s[256];
  const int t = threadIdx.x;
  int carry = 0;
  for (int base = 0; base < nb; base += 256) {
    int v = (base + t < nb) ? partial[base + t] : 0;
    s[t] = v;
    __syncthreads();
    for (int off = 1; off < 256; off <<= 1) {
      int add = (t >= off) ? s[t - off] : 0;
      __syncthreads();
      s[t] += add;
      __syncthreads();
    }
    if (base + t < nb) partial[base + t] = s[t] - v + carry;
    carry += s[255];
    __syncthreads();
  }
  if (t == 0) *total_out = carry;
}

__global__ void block_scan(int* __restrict__ cnt_cursor, const int* __restrict__ partial,
                           int* __restrict__ rowptr, int n) {
  __shared__ int s[256];
  const int t = threadIdx.x;
  const int base = blockIdx.x * 1024;
  int v[4];
  int sum = 0;
#pragma unroll
  for (int j = 0; j < 4; ++j) {
    int idx = base + t * 4 + j;
    v[j] = (idx < n) ? cnt_cursor[idx] : 0;
    sum += v[j];
  }
  s[t] = sum;
  __syncthreads();
  for (int off = 1; off < 256; off <<= 1) {
    int add = (t >= off) ? s[t - off] : 0;
    __syncthreads();
    s[t] += add;
    __syncthreads();
  }
  int excl = s[t] - sum + partial[blockIdx.x];
#pragma unroll
  for (int j = 0; j < 4; ++j) {
    int idx = base + t * 4 + j;
    if (idx < n) {
      rowptr[idx] = excl;
      cnt_cursor[idx] = excl;
    }
    excl += v[j];
  }
}

__global__ void build_kernel(const int* __restrict__ src, const int* __restrict__ dst,
                             int* __restrict__ cursor, int* __restrict__ srcList, int E) {
  int i = blockIdx.x * 256 + threadIdx.x;
  if (i < E) {
    int pos = atomicAdd(&cursor[dst[i]], 1);
    srcList[pos] = src[i];
  }
}

// ---------------- W transpose+convert: Wt[n][k] bf16, K zero-padded ---------

struct WConvArgs {
  const float* w[6];
  unsigned short* o[6];
  int K[6], Kp[6];
};

__global__ void wconv(WConvArgs a) {
  const int wi = blockIdx.y;
  const int i = blockIdx.x * 256 + threadIdx.x;
  const int Kp = a.Kp[wi];
  if (i >= H * Kp) return;
  const int nn = i / Kp, k = i - nn * Kp;
  float v = (k < a.K[wi]) ? a.w[wi][(size_t)k * H + nn] : 0.f;
  a.o[wi][(size_t)nn * Kp + k] = f2bf(v);
}

// ---------------- Aggregation (gather), bf16 h ------------------------------
// out[i] = h[i] + sum_{j in in(i)} h[j]; one wave per node, one dword
// (2 bf16 features) per lane -> a single wave-load covers the 256B row.

__global__ void gather_h(const unsigned short* __restrict__ h, const int* __restrict__ rowptr,
                         const int* __restrict__ srcList, unsigned short* __restrict__ out, int n) {
  const int node = blockIdx.x;
  const int lane = threadIdx.x;           // 64
  const unsigned* h2 = (const unsigned*)h;
  const int beg = rowptr[node], end = rowptr[node + 1];
  unsigned self = h2[(size_t)node * 64 + lane];
  float a0 = bf2f((unsigned short)self);
  float a1 = bf2f((unsigned short)(self >> 16));
  int i = beg;
  for (; i + 3 < end; i += 4) {
    int s0 = srcList[i], s1 = srcList[i + 1], s2 = srcList[i + 2], s3 = srcList[i + 3];
    unsigned v0 = h2[(size_t)s0 * 64 + lane];
    unsigned v1 = h2[(size_t)s1 * 64 + lane];
    unsigned v2 = h2[(size_t)s2 * 64 + lane];
    unsigned v3 = h2[(size_t)s3 * 64 + lane];
    a0 += (bf2f((unsigned short)v0) + bf2f((unsigned short)v1)) +
          (bf2f((unsigned short)v2) + bf2f((unsigned short)v3));
    a1 += (bf2f((unsigned short)(v0 >> 16)) + bf2f((unsigned short)(v1 >> 16))) +
          (bf2f((unsigned short)(v2 >> 16)) + bf2f((unsigned short)(v3 >> 16)));
  }
  for (; i < end; ++i) {
    unsigned v = h2[(size_t)srcList[i] * 64 + lane];
    a0 += bf2f((unsigned short)v);
    a1 += bf2f((unsigned short)(v >> 16));
  }
  unsigned packed = ((unsigned)f2bf(a1) << 16) | (unsigned)f2bf(a0);
  ((unsigned*)out)[(size_t)node * 64 + lane] = packed;
}

// Layer-1 gather: fp32 x (N x 33) -> bf16 A (N x 64, zero-padded).
__global__ void gather_x(const float* __restrict__ x, const int* __restrict__ rowptr,
                         const int* __restrict__ srcList, unsigned short* __restrict__ out, int n) {
  const int node = blockIdx.x;
  const int lane = threadIdx.x;           // 64
  const int beg = rowptr[node], end = rowptr[node + 1];
  float acc = 0.f;
  if (lane < F_IN) acc = x[(size_t)node * F_IN + lane];
  int i = beg;
  for (; i + 3 < end; i += 4) {
    int s0 = srcList[i], s1 = srcList[i + 1], s2 = srcList[i + 2], s3 = srcList[i + 3];
    if (lane < F_IN) {
      float v0 = x[(size_t)s0 * F_IN + lane];
      float v1 = x[(size_t)s1 * F_IN + lane];
      float v2 = x[(size_t)s2 * F_IN + lane];
      float v3 = x[(size_t)s3 * F_IN + lane];
      acc += (v0 + v1) + (v2 + v3);
    }
  }
  for (; i < end; ++i) {
    if (lane < F_IN) acc += x[(size_t)srcList[i] * F_IN + lane];
  }
  out[(size_t)node * 64 + lane] = f2bf(acc);   // lanes >=33 write bf16(0)=0
}

// ---------------- MFMA GEMM: C[n x 128] = A[n x K] @ W[K x 128] -------------
// bf16 inputs, fp32 accumulate. 64x128 tile per block, 256 thr = 4 waves,
// each wave: 16 rows x 128 cols = 8 MFMA tiles (16x16x32), K-loop in LDS.
// LDS stride padded +8 ushorts (16B): fragment reads are 2-way aliased (free).

template <int K, bool BN, bool POOL, bool STORE>
__global__ __launch_bounds__(256) void mfma_gemm(
    const unsigned short* __restrict__ A,   // n x K bf16
    const unsigned short* __restrict__ Wt,  // 128 x K bf16 (Wt[n][k] = W[k][n])
    const float* __restrict__ bias,
    const float* __restrict__ gam, const float* __restrict__ bet,
    const float* __restrict__ mu,  const float* __restrict__ var,
    unsigned short* __restrict__ out, const int* __restrict__ batch,
    float* __restrict__ pool, int n) {
  constexpr int KP = K + 8;
  __shared__ __align__(16) unsigned short Als[64 * KP];
  __shared__ __align__(16) unsigned short Wls[128 * KP];
  const int tx = threadIdx.x;
  const int rowBase = blockIdx.x * 64;

  // Stage A tile (16B per thread per iter), rows >= n -> zeros.
  constexpr int ACH = K / 8;              // 8-ushort chunks per row
  for (int i = tx; i < 64 * ACH; i += 256) {
    int r = i / ACH, c8 = (i % ACH) * 8;
    int row = rowBase + r;
    uint4 val = make_uint4(0, 0, 0, 0);
    if (row < n) val = *(const uint4*)(A + (size_t)row * K + c8);
    *(uint4*)(&Als[r * KP + c8]) = val;
  }
  // Stage Wt (full 128 x K).
  for (int i = tx; i < 128 * ACH; i += 256) {
    int r = i / ACH, c8 = (i % ACH) * 8;
    uint4 val = *(const uint4*)(Wt + (size_t)r * K + c8);
    *(uint4*)(&Wls[r * KP + c8]) = val;
  }
  __syncthreads();

  const int lane = tx & 63;
  const int q = lane >> 4, m = lane & 15;
  const int waveRow = (tx >> 6) * 16;

  f32x4 acc[8];
#pragma unroll
  for (int t = 0; t < 8; ++t) acc[t] = (f32x4)(0.f);

#pragma unroll
  for (int kc = 0; kc < K / 32; ++kc) {
    short8 af = *(const short8*)(&Als[(waveRow + m) * KP + kc * 32 + q * 8]);
#pragma unroll
    for (int t = 0; t < 8; ++t) {
      short8 bf = *(const short8*)(&Wls[(t * 16 + m) * KP + kc * 32 + q * 8]);
      acc[t] = __builtin_amdgcn_mfma_f32_16x16x32_bf16(af, bf, acc[t], 0, 0, 0);
    }
  }

  // Epilogue. Lane owns rows r0..r0+3 (contiguous), cols t*16+m.
  const int r0 = rowBase + waveRow + q * 4;
  int gb4[4];
  if constexpr (POOL) {
#pragma unroll
    for (int reg = 0; reg < 4; ++reg) gb4[reg] = (r0 + reg < n) ? batch[r0 + reg] : -1;
  }
#pragma unroll
  for (int t = 0; t < 8; ++t) {
    const int col = t * 16 + m;
    const float bi = bias[col];
    float scv = 1.f, shv = 0.f;
    if constexpr (BN) {
      scv = gam[col] * rsqrtf(var[col] + 1e-5f);
      shv = bet[col] - mu[col] * scv;
    }
    float v[4];
#pragma unroll
    for (int reg = 0; reg < 4; ++reg) {
      float z = acc[t][reg] + bi;
      if constexpr (BN) z = fmaf(z, scv, shv);
      v[reg] = z > 0.f ? z : 0.f;
    }
    if constexpr (STORE) {
#pragma unroll
      for (int reg = 0; reg < 4; ++reg) {
        int row = r0 + reg;
        if (row < n) out[(size_t)row * H + col] = f2bf(v[reg]);
      }
    }
    if constexpr (POOL) {
      int gcur = -1;
      float ps = 0.f;
#pragma unroll
      for (int reg = 0; reg < 4; ++reg) {
        if (gb4[reg] < 0) break;
        if (gb4[reg] != gcur) {
          if (gcur >= 0) atomicAdd(pool + gcur * H + col, ps);
          gcur = gb4[reg];
          ps = v[reg];
        } else {
          ps += v[reg];
        }
      }
      if (gcur >= 0) atomicAdd(pool + gcur * H + col, ps);
    }
  }
}

// ---------------- Head MLP: [G,384] -> 50 -> 20 -> 1 -> sigmoid -------------

__global__ void head_kernel(const float* __restrict__ pools,
                            const float* __restrict__ l1w, const float* __restrict__ l1b,
                            const float* __restrict__ l2w, const float* __restrict__ l2b,
                            const float* __restrict__ l3w, const float* __restrict__ l3b,
                            float* __restrict__ out) {
  const int g = blockIdx.x;
  const int t = threadIdx.x;  // 64 threads
  __shared__ float hin[3 * H];
  __shared__ float t1[50];
  __shared__ float t2[20];
  for (int idx = t; idx < 3 * H; idx += 64) {
    int l = idx >> 7, f = idx & 127;
    hin[idx] = pools[(size_t)l * GG * H + (size_t)g * H + f];
  }
  __syncthreads();
  if (t < 50) {
    float s = l1b[t];
    for (int k = 0; k < 3 * H; ++k) s = fmaf(hin[k], l1w[k * 50 + t], s);
    t1[t] = s > 0.f ? s : 0.f;
  }
  __syncthreads();
  if (t < 20) {
    float s = l2b[t];
    for (int k = 0; k < 50; ++k) s = fmaf(t1[k], l2w[k * 20 + t], s);
    t2[t] = s > 0.f ? s : 0.f;
  }
  __syncthreads();
  if (t == 0) {
    float s = l3b[0];
    for (int k = 0; k < 20; ++k) s = fmaf(t2[k], l3w[k], s);
    out[g] = 1.f / (1.f + expf(-s));
  }
}

// ---------------- launch ----------------------------------------------------

extern "C" void kernel_launch(void* const* d_in, const int* in_sizes, int n_in,
                              void* d_out, int out_size, void* d_ws, size_t ws_size,
                              hipStream_t stream) {
  const float* x    = (const float*)d_in[0];
  const int* ei     = (const int*)d_in[1];
  const int* batch  = (const int*)d_in[2];
  const int N = in_sizes[2];
  const int E = in_sizes[1] / 2;
  const int* src = ei;
  const int* dst = ei + E;

  const float* w1[3]; const float* b1[3]; const float* gm[3]; const float* be[3];
  const float* mu[3]; const float* vr[3]; const float* w2[3]; const float* b2[3];
  for (int l = 0; l < 3; ++l) {
    int b = 3 + 8 * l;
    w1[l] = (const float*)d_in[b + 0];
    b1[l] = (const float*)d_in[b + 1];
    gm[l] = (const float*)d_in[b + 2];
    be[l] = (const float*)d_in[b + 3];
    mu[l] = (const float*)d_in[b + 4];
    vr[l] = (const float*)d_in[b + 5];
    w2[l] = (const float*)d_in[b + 6];
    b2[l] = (const float*)d_in[b + 7];
  }
  const float* l1w = (const float*)d_in[27];
  const float* l1b = (const float*)d_in[28];
  const float* l2w = (const float*)d_in[29];
  const float* l2b = (const float*)d_in[30];
  const float* l3w = (const float*)d_in[31];
  const float* l3b = (const float*)d_in[32];

  // workspace carve-up
  char* ws = (char*)d_ws;
  size_t off = 0;
  auto take = [&](size_t bytes) {
    size_t p = off;
    off += (bytes + 255) & ~(size_t)255;
    return p;
  };
  unsigned short* A = (unsigned short*)(ws + take((size_t)N * H * 2));  // bf16 (layer1: stride 64)
  unsigned short* Z = (unsigned short*)(ws + take((size_t)N * H * 2));  // bf16
  unsigned short* P = (unsigned short*)(ws + take((size_t)N * H * 2));  // bf16
  float* pools  = (float*)(ws + take((size_t)3 * GG * H * 4));
  int* rowptr   = (int*)(ws + take((size_t)(N + 1) * 4));
  int* cursor   = (int*)(ws + take((size_t)N * 4));
  int* srcList  = (int*)(ws + take((size_t)E * 4));
  int* partial  = (int*)(ws + take((size_t)1024 * 4));
  unsigned short* Wt[6];
  for (int i = 0; i < 6; ++i) Wt[i] = (unsigned short*)(ws + take((size_t)H * H * 2));
  (void)ws_size; (void)n_in; (void)out_size;

  const int eb = (E + 255) / 256;
  const int gb = (N + 63) / 64;
  const int nb = (N + 1023) / 1024;

  hipMemsetAsync(cursor, 0, (size_t)N * 4, stream);
  hipMemsetAsync(pools, 0, (size_t)3 * GG * H * 4, stream);

  // W transpose+convert (all 6 in one launch)
  WConvArgs wa;
  wa.w[0] = w1[0]; wa.K[0] = F_IN; wa.Kp[0] = 64;
  wa.w[1] = w2[0]; wa.K[1] = H;    wa.Kp[1] = H;
  wa.w[2] = w1[1]; wa.K[2] = H;    wa.Kp[2] = H;
  wa.w[3] = w2[1]; wa.K[3] = H;    wa.Kp[3] = H;
  wa.w[4] = w1[2]; wa.K[4] = H;    wa.Kp[4] = H;
  wa.w[5] = w2[2]; wa.K[5] = H;    wa.Kp[5] = H;
  for (int i = 0; i < 6; ++i) wa.o[i] = Wt[i];
  wconv<<<dim3((H * H + 255) / 256, 6), 256, 0, stream>>>(wa);

  // CSR by dst
  hist_kernel<<<eb, 256, 0, stream>>>(dst, cursor, E);
  block_reduce<<<nb, 256, 0, stream>>>(cursor, partial, N);
  scan_partials<<<1, 256, 0, stream>>>(partial, nb, rowptr + N);
  block_scan<<<nb, 256, 0, stream>>>(cursor, partial, rowptr, N);
  build_kernel<<<eb, 256, 0, stream>>>(src, dst, cursor, srcList, E);

  // ---- layer 1 (K padded 33 -> 64) ----
  gather_x<<<N, 64, 0, stream>>>(x, rowptr, srcList, A, N);
  mfma_gemm<64, true, false, true><<<gb, 256, 0, stream>>>(
      A, Wt[0], b1[0], gm[0], be[0], mu[0], vr[0], Z, nullptr, nullptr, N);
  mfma_gemm<128, false, true, true><<<gb, 256, 0, stream>>>(
      Z, Wt[1], b2[0], nullptr, nullptr, nullptr, nullptr, P, batch, pools, N);

  // ---- layer 2 ----
  gather_h<<<N, 64, 0, stream>>>(P, rowptr, srcList, A, N);
  mfma_gemm<128, true, false, true><<<gb, 256, 0, stream>>>(
      A, Wt[2], b1[1], gm[1], be[1], mu[1], vr[1], Z, nullptr, nullptr, N);
  mfma_gemm<128, false, true, true><<<gb, 256, 0, stream>>>(
      Z, Wt[3], b2[1], nullptr, nullptr, nullptr, nullptr, P, batch, pools + GG * H, N);

  // ---- layer 3 (h3 pooled only) ----
  gather_h<<<N, 64, 0, stream>>>(P, rowptr, srcList, A, N);
  mfma_gemm<128, true, false, true><<<gb, 256, 0, stream>>>(
      A, Wt[4], b1[2], gm[2], be[2], mu[2], vr[2], Z, nullptr, nullptr, N);
  mfma_gemm<128, false, true, false><<<gb, 256, 0, stream>>>(
      Z, Wt[5], b2[2], nullptr, nullptr, nullptr, nullptr, nullptr, batch, pools + 2 * GG * H, N);

  // ---- head ----
  head_kernel<<<GG, 64, 0, stream>>>(pools, l1w, l1b, l2w, l2b, l3w, l3b, (float*)d_out);
}

// Round 4
// 491.678 us; speedup vs baseline: 1.4120x; 1.0694x over previous
//
#include <hip/hip_runtime.h>
#include <math.h>

// N=50000 nodes, E=800000 edges, F_IN=33, H=128, G=64 graphs.
static constexpr int F_IN = 33;
static constexpr int H    = 128;
static constexpr int GG   = 64;

typedef __attribute__((ext_vector_type(8))) short short8;
typedef __attribute__((ext_vector_type(4))) float f32x4;

__device__ __forceinline__ unsigned short f2bf(float f) {
  union { float f; unsigned u; } v; v.f = f;
  unsigned r = v.u + 0x7fffu + ((v.u >> 16) & 1u);   // RNE
  return (unsigned short)(r >> 16);
}
__device__ __forceinline__ float bf2f(unsigned short b) {
  union { unsigned u; float f; } v; v.u = ((unsigned)b) << 16;
  return v.f;
}

// Async global->LDS copy, 16B per lane, wave-uniform LDS base (lane-linear).
using gas_u32 = const __attribute__((address_space(1))) unsigned int*;
using las_u32 = __attribute__((address_space(3))) unsigned int*;
__device__ __forceinline__ void ld_lds16(const unsigned short* g, unsigned short* l) {
  __builtin_amdgcn_global_load_lds((gas_u32)(const void*)g, (las_u32)(void*)l, 16, 0, 0);
}

// ---------------- CSR build ----------------

__global__ void hist_kernel(const int* __restrict__ dst, int* __restrict__ cnt, int E) {
  int i = blockIdx.x * 256 + threadIdx.x;
  if (i < E) atomicAdd(&cnt[dst[i]], 1);
}

__global__ void block_reduce(const int* __restrict__ cnt, int* __restrict__ partial, int n) {
  __shared__ int s[256];
  const int t = threadIdx.x;
  const int base = blockIdx.x * 1024;
  int sum = 0;
  for (int i = t; i < 1024; i += 256) {
    int idx = base + i;
    if (idx < n) sum += cnt[idx];
  }
  s[t] = sum;
  __syncthreads();
  for (int off = 128; off > 0; off >>= 1) {
    if (t < off) s[t] += s[t + off];
    __syncthreads();
  }
  if (t == 0) partial[blockIdx.x] = s[0];
}

__global__ void scan_partials(int* __restrict__ partial, int nb, int* __restrict__ total_out) {
  __shared__ int s[256];
  const int t = threadIdx.x;
  int carry = 0;
  for (int base = 0; base < nb; base += 256) {
    int v = (base + t < nb) ? partial[base + t] : 0;
    s[t] = v;
    __syncthreads();
    for (int off = 1; off < 256; off <<= 1) {
      int add = (t >= off) ? s[t - off] : 0;
      __syncthreads();
      s[t] += add;
      __syncthreads();
    }
    if (base + t < nb) partial[base + t] = s[t] - v + carry;
    carry += s[255];
    __syncthreads();
  }
  if (t == 0) *total_out = carry;
}

__global__ void block_scan(int* __restrict__ cnt_cursor, const int* __restrict__ partial,
                           int* __restrict__ rowptr, int n) {
  __shared__ int s[256];
  const int t = threadIdx.x;
  const int base = blockIdx.x * 1024;
  int v[4];
  int sum = 0;
#pragma unroll
  for (int j = 0; j < 4; ++j) {
    int idx = base + t * 4 + j;
    v[j] = (idx < n) ? cnt_cursor[idx] : 0;
    sum += v[j];
  }
  s[t] = sum;
  __syncthreads();
  for (int off = 1; off < 256; off <<= 1) {
    int add = (t >= off) ? s[t - off] : 0;
    __syncthreads();
    s[t] += add;
    __syncthreads();
  }
  int excl = s[t] - sum + partial[blockIdx.x];
#pragma unroll
  for (int j = 0; j < 4; ++j) {
    int idx = base + t * 4 + j;
    if (idx < n) {
      rowptr[idx] = excl;
      cnt_cursor[idx] = excl;
    }
    excl += v[j];
  }
}

__global__ void build_kernel(const int* __restrict__ src, const int* __restrict__ dst,
                             int* __restrict__ cursor, int* __restrict__ srcList, int E) {
  int i = blockIdx.x * 256 + threadIdx.x;
  if (i < E) {
    int pos = atomicAdd(&cursor[dst[i]], 1);
    srcList[pos] = src[i];
  }
}

// ------- W transpose+convert to bf16, XOR-swizzled 16B chunks per row -------
// o[n][ (chunk^ (n&7))*8 + k%8 ] = W[k][n]; chunk = k/8. K zero-padded to Kp.

struct WConvArgs {
  const float* w[6];
  unsigned short* o[6];
  int K[6], Kp[6];
};

__global__ void wconv(WConvArgs a) {
  const int wi = blockIdx.y;
  const int i = blockIdx.x * 256 + threadIdx.x;
  const int Kp = a.Kp[wi];
  if (i >= H * Kp) return;
  const int nn = i / Kp, k = i - nn * Kp;
  float v = (k < a.K[wi]) ? a.w[wi][(size_t)k * H + nn] : 0.f;
  a.o[wi][(size_t)nn * Kp + (((k >> 3) ^ (nn & 7)) << 3) + (k & 7)] = f2bf(v);
}

// ---------------- Aggregation (gather), bf16 h, swizzled rows ---------------
// Logical dword d of row r lives at r*64 + ((d>>2)^(r&7))*4 + (d&3).

__global__ void gather_h(const unsigned short* __restrict__ h, const int* __restrict__ rowptr,
                         const int* __restrict__ srcList, unsigned short* __restrict__ out, int n) {
  const int node = blockIdx.x;
  const int lane = threadIdx.x;           // 64
  const unsigned* h2 = (const unsigned*)h;
  const int c4 = lane >> 2, w4 = lane & 3;
  const int beg = rowptr[node], end = rowptr[node + 1];
  unsigned self = h2[(size_t)node * 64 + ((c4 ^ (node & 7)) << 2) + w4];
  float a0 = bf2f((unsigned short)self);
  float a1 = bf2f((unsigned short)(self >> 16));
  int i = beg;
  for (; i + 3 < end; i += 4) {
    int s0 = srcList[i], s1 = srcList[i + 1], s2 = srcList[i + 2], s3 = srcList[i + 3];
    unsigned v0 = h2[(size_t)s0 * 64 + ((c4 ^ (s0 & 7)) << 2) + w4];
    unsigned v1 = h2[(size_t)s1 * 64 + ((c4 ^ (s1 & 7)) << 2) + w4];
    unsigned v2 = h2[(size_t)s2 * 64 + ((c4 ^ (s2 & 7)) << 2) + w4];
    unsigned v3 = h2[(size_t)s3 * 64 + ((c4 ^ (s3 & 7)) << 2) + w4];
    a0 += (bf2f((unsigned short)v0) + bf2f((unsigned short)v1)) +
          (bf2f((unsigned short)v2) + bf2f((unsigned short)v3));
    a1 += (bf2f((unsigned short)(v0 >> 16)) + bf2f((unsigned short)(v1 >> 16))) +
          (bf2f((unsigned short)(v2 >> 16)) + bf2f((unsigned short)(v3 >> 16)));
  }
  for (; i < end; ++i) {
    int s0 = srcList[i];
    unsigned v = h2[(size_t)s0 * 64 + ((c4 ^ (s0 & 7)) << 2) + w4];
    a0 += bf2f((unsigned short)v);
    a1 += bf2f((unsigned short)(v >> 16));
  }
  unsigned packed = ((unsigned)f2bf(a1) << 16) | (unsigned)f2bf(a0);
  ((unsigned*)out)[(size_t)node * 64 + ((c4 ^ (node & 7)) << 2) + w4] = packed;
}

// Layer-1 gather: fp32 x (N x 33) -> bf16 A (N x 64 ushorts, swizzled rows).
__global__ void gather_x(const float* __restrict__ x, const int* __restrict__ rowptr,
                         const int* __restrict__ srcList, unsigned short* __restrict__ out, int n) {
  const int node = blockIdx.x;
  const int lane = threadIdx.x;           // 64
  const int beg = rowptr[node], end = rowptr[node + 1];
  float acc = 0.f;
  if (lane < F_IN) acc = x[(size_t)node * F_IN + lane];
  int i = beg;
  for (; i + 3 < end; i += 4) {
    int s0 = srcList[i], s1 = srcList[i + 1], s2 = srcList[i + 2], s3 = srcList[i + 3];
    if (lane < F_IN) {
      float v0 = x[(size_t)s0 * F_IN + lane];
      float v1 = x[(size_t)s1 * F_IN + lane];
      float v2 = x[(size_t)s2 * F_IN + lane];
      float v3 = x[(size_t)s3 * F_IN + lane];
      acc += (v0 + v1) + (v2 + v3);
    }
  }
  for (; i < end; ++i) {
    if (lane < F_IN) acc += x[(size_t)srcList[i] * F_IN + lane];
  }
  out[(size_t)node * 64 + (((lane >> 3) ^ (node & 7)) << 3) + (lane & 7)] = f2bf(acc);
}

// -------- Fused GIN MLP: C = relu(relu(BN(A@W1)) @ W2 + b2), + pool ---------
// Persistent blocks (grid=256, 1 block/CU): W1,W2 staged to LDS ONCE (async),
// 64-row tiles pulled via global atomic ticket. Z stays in LDS. 512 thr =
// 8 waves: wave w -> rows (w>>1)*16.., cols (w&1)*64.. (4 MFMA col-tiles).

template <int K1, bool STORE>
__global__ __launch_bounds__(512, 1) void gin_mlp(
    const unsigned short* __restrict__ Ag,   // n x K1 bf16 (swizzled rows)
    const unsigned short* __restrict__ W1t,  // 128 x K1 bf16 (swizzled)
    const unsigned short* __restrict__ W2t,  // 128 x 128 bf16 (swizzled)
    const float* __restrict__ b1, const float* __restrict__ gam,
    const float* __restrict__ bet, const float* __restrict__ mu,
    const float* __restrict__ var, const float* __restrict__ b2,
    unsigned short* __restrict__ Pout,       // n x 128 bf16 (swizzled) or null
    const int* __restrict__ batch, float* __restrict__ pool,
    int* __restrict__ tick, int n) {
  __shared__ __align__(16) unsigned short W1ls[128 * K1];
  __shared__ __align__(16) unsigned short W2ls[128 * 128];
  __shared__ __align__(16) unsigned short Als[64 * K1];
  __shared__ __align__(16) unsigned short Zls[64 * 128];
  __shared__ float sc1[128], sh1[128], b2l[128];
  __shared__ int sT;

  const int tx = threadIdx.x;
  const int wv = tx >> 6;                 // wave 0..7
  const int lane = tx & 63;
  const int q = lane >> 4, m = lane & 15;
  const int rowGroup = (wv >> 1) * 16;    // 0,16,32,48
  const int colHalf = (wv & 1) * 64;
  const int ntiles = (n + 63) >> 6;

  // Stage W once (async; each wave copies distinct 1024B segments).
  constexpr int W1SEG = 128 * K1 / 512;
  for (int s = wv; s < W1SEG; s += 8)
    ld_lds16(W1t + s * 512 + lane * 8, &W1ls[s * 512]);
  for (int s = wv; s < 32; s += 8)
    ld_lds16(W2t + s * 512 + lane * 8, &W2ls[s * 512]);

  if (tx < 128) {                          // fold bias1 into BN affine
    float s = gam[tx] * rsqrtf(var[tx] + 1e-5f);
    sc1[tx] = s;
    sh1[tx] = bet[tx] + (b1[tx] - mu[tx]) * s;
  } else if (tx < 256) {
    b2l[tx - 128] = b2[tx - 128];
  }
  if (tx == 0) sT = atomicAdd(tick, 1);
  __syncthreads();                         // drains W loads, publishes sT

  int tile = sT;
  constexpr int ASEG = 64 * K1 / 512;
  if (tile < ntiles) {
    const unsigned short* src = Ag + (size_t)tile * 64 * K1;
    for (int s = wv; s < ASEG; s += 8)
      ld_lds16(src + s * 512 + lane * 8, &Als[s * 512]);
  }
  __syncthreads();                         // A(tile) ready

  while (tile < ntiles) {
    // ---- GEMM1: Z = relu(BN(A @ W1 + b1)) ----
    f32x4 acc[4];
#pragma unroll
    for (int t4 = 0; t4 < 4; ++t4) acc[t4] = (f32x4)(0.f);
    const int am = rowGroup + m;
#pragma unroll
    for (int kc = 0; kc < K1 / 32; ++kc) {
      short8 af = *(const short8*)&Als[am * K1 + (((kc * 4 + q) ^ (am & 7)) << 3)];
#pragma unroll
      for (int t4 = 0; t4 < 4; ++t4) {
        const int bn = colHalf + t4 * 16 + m;
        short8 bf = *(const short8*)&W1ls[bn * K1 + (((kc * 4 + q) ^ (bn & 7)) << 3)];
        acc[t4] = __builtin_amdgcn_mfma_f32_16x16x32_bf16(af, bf, acc[t4], 0, 0, 0);
      }
    }
#pragma unroll
    for (int t4 = 0; t4 < 4; ++t4) {       // epilogue -> Zls (bf16, swizzled)
      const int col = colHalf + t4 * 16 + m;
      const float s = sc1[col], hh = sh1[col];
#pragma unroll
      for (int reg = 0; reg < 4; ++reg) {
        const int r = rowGroup + q * 4 + reg;
        float z = fmaf(acc[t4][reg], s, hh);
        z = z > 0.f ? z : 0.f;
        Zls[r * 128 + (((col >> 3) ^ (r & 7)) << 3) + (col & 7)] = f2bf(z);
      }
    }
    if (tx == 0) sT = atomicAdd(tick, 1);
    __syncthreads();                       // publishes Zls + next ticket
    const int nt = sT;
    if (nt < ntiles) {                     // prefetch next A, overlaps GEMM2
      const unsigned short* src = Ag + (size_t)nt * 64 * K1;
      for (int s = wv; s < ASEG; s += 8)
        ld_lds16(src + s * 512 + lane * 8, &Als[s * 512]);
    }
    // ---- GEMM2: C = relu(Z @ W2 + b2) ----
#pragma unroll
    for (int t4 = 0; t4 < 4; ++t4) acc[t4] = (f32x4)(0.f);
#pragma unroll
    for (int kc = 0; kc < 4; ++kc) {
      short8 af = *(const short8*)&Zls[am * 128 + (((kc * 4 + q) ^ (am & 7)) << 3)];
#pragma unroll
      for (int t4 = 0; t4 < 4; ++t4) {
        const int bn = colHalf + t4 * 16 + m;
        short8 bf = *(const short8*)&W2ls[bn * 128 + (((kc * 4 + q) ^ (bn & 7)) << 3)];
        acc[t4] = __builtin_amdgcn_mfma_f32_16x16x32_bf16(af, bf, acc[t4], 0, 0, 0);
      }
    }
    const int r0 = tile * 64 + rowGroup + q * 4;
    int gb4[4];
#pragma unroll
    for (int reg = 0; reg < 4; ++reg) gb4[reg] = (r0 + reg < n) ? batch[r0 + reg] : -1;
#pragma unroll
    for (int t4 = 0; t4 < 4; ++t4) {
      const int col = colHalf + t4 * 16 + m;
      float v[4];
#pragma unroll
      for (int reg = 0; reg < 4; ++reg) {
        float z = acc[t4][reg] + b2l[col];
        v[reg] = z > 0.f ? z : 0.f;
      }
      if constexpr (STORE) {
#pragma unroll
        for (int reg = 0; reg < 4; ++reg) {
          const int row = r0 + reg;
          if (row < n)
            Pout[(size_t)row * 128 + (((col >> 3) ^ (row & 7)) << 3) + (col & 7)] = f2bf(v[reg]);
        }
      }
      int gcur = -1; float ps = 0.f;       // batch sorted -> run-length flush
#pragma unroll
      for (int reg = 0; reg < 4; ++reg) {
        if (gb4[reg] < 0) break;
        if (gb4[reg] != gcur) {
          if (gcur >= 0) atomicAdd(pool + gcur * H + col, ps);
          gcur = gb4[reg]; ps = v[reg];
        } else {
          ps += v[reg];
        }
      }
      if (gcur >= 0) atomicAdd(pool + gcur * H + col, ps);
    }
    __syncthreads();                       // drains prefetch+stores; Zls free
    tile = nt;
  }
}

// ---------------- Head MLP: [G,384] -> 50 -> 20 -> 1 -> sigmoid -------------

__global__ void head_kernel(const float* __restrict__ pools,
                            const float* __restrict__ l1w, const float* __restrict__ l1b,
                            const float* __restrict__ l2w, const float* __restrict__ l2b,
                            const float* __restrict__ l3w, const float* __restrict__ l3b,
                            float* __restrict__ out) {
  const int g = blockIdx.x;
  const int t = threadIdx.x;  // 64 threads
  __shared__ float hin[3 * H];
  __shared__ float t1[50];
  __shared__ float t2[20];
  for (int idx = t; idx < 3 * H; idx += 64) {
    int l = idx >> 7, f = idx & 127;
    hin[idx] = pools[(size_t)l * GG * H + (size_t)g * H + f];
  }
  __syncthreads();
  if (t < 50) {
    float s = l1b[t];
    for (int k = 0; k < 3 * H; ++k) s = fmaf(hin[k], l1w[k * 50 + t], s);
    t1[t] = s > 0.f ? s : 0.f;
  }
  __syncthreads();
  if (t < 20) {
    float s = l2b[t];
    for (int k = 0; k < 50; ++k) s = fmaf(t1[k], l2w[k * 20 + t], s);
    t2[t] = s > 0.f ? s : 0.f;
  }
  __syncthreads();
  if (t == 0) {
    float s = l3b[0];
    for (int k = 0; k < 20; ++k) s = fmaf(t2[k], l3w[k], s);
    out[g] = 1.f / (1.f + expf(-s));
  }
}

// ---------------- launch ----------------------------------------------------

extern "C" void kernel_launch(void* const* d_in, const int* in_sizes, int n_in,
                              void* d_out, int out_size, void* d_ws, size_t ws_size,
                              hipStream_t stream) {
  const float* x    = (const float*)d_in[0];
  const int* ei     = (const int*)d_in[1];
  const int* batch  = (const int*)d_in[2];
  const int N = in_sizes[2];
  const int E = in_sizes[1] / 2;
  const int* src = ei;
  const int* dst = ei + E;

  const float* w1[3]; const float* b1[3]; const float* gm[3]; const float* be[3];
  const float* mu[3]; const float* vr[3]; const float* w2[3]; const float* b2[3];
  for (int l = 0; l < 3; ++l) {
    int b = 3 + 8 * l;
    w1[l] = (const float*)d_in[b + 0];
    b1[l] = (const float*)d_in[b + 1];
    gm[l] = (const float*)d_in[b + 2];
    be[l] = (const float*)d_in[b + 3];
    mu[l] = (const float*)d_in[b + 4];
    vr[l] = (const float*)d_in[b + 5];
    w2[l] = (const float*)d_in[b + 6];
    b2[l] = (const float*)d_in[b + 7];
  }
  const float* l1w = (const float*)d_in[27];
  const float* l1b = (const float*)d_in[28];
  const float* l2w = (const float*)d_in[29];
  const float* l2b = (const float*)d_in[30];
  const float* l3w = (const float*)d_in[31];
  const float* l3b = (const float*)d_in[32];

  // workspace carve-up
  char* ws = (char*)d_ws;
  size_t off = 0;
  auto take = [&](size_t bytes) {
    size_t p = off;
    off += (bytes + 255) & ~(size_t)255;
    return p;
  };
  unsigned short* A = (unsigned short*)(ws + take((size_t)N * H * 2));  // agg (bf16, swizzled)
  unsigned short* P = (unsigned short*)(ws + take((size_t)N * H * 2));  // layer out (bf16, swizzled)
  float* pools  = (float*)(ws + take((size_t)3 * GG * H * 4));
  int* tick     = (int*)(ws + take(256));
  int* rowptr   = (int*)(ws + take((size_t)(N + 1) * 4));
  int* cursor   = (int*)(ws + take((size_t)N * 4));
  int* srcList  = (int*)(ws + take((size_t)E * 4));
  int* partial  = (int*)(ws + take((size_t)1024 * 4));
  unsigned short* Wt[6];
  for (int i = 0; i < 6; ++i) Wt[i] = (unsigned short*)(ws + take((size_t)H * H * 2));
  (void)ws_size; (void)n_in; (void)out_size;

  const int eb = (E + 255) / 256;
  const int nb = (N + 1023) / 1024;

  hipMemsetAsync(cursor, 0, (size_t)N * 4, stream);
  hipMemsetAsync(pools, 0, (size_t)3 * GG * H * 4, stream);
  hipMemsetAsync(tick, 0, 256, stream);

  // W transpose+convert+swizzle (all 6 in one launch)
  WConvArgs wa;
  wa.w[0] = w1[0]; wa.K[0] = F_IN; wa.Kp[0] = 64;
  wa.w[1] = w2[0]; wa.K[1] = H;    wa.Kp[1] = H;
  wa.w[2] = w1[1]; wa.K[2] = H;    wa.Kp[2] = H;
  wa.w[3] = w2[1]; wa.K[3] = H;    wa.Kp[3] = H;
  wa.w[4] = w1[2]; wa.K[4] = H;    wa.Kp[4] = H;
  wa.w[5] = w2[2]; wa.K[5] = H;    wa.Kp[5] = H;
  for (int i = 0; i < 6; ++i) wa.o[i] = Wt[i];
  wconv<<<dim3((H * H + 255) / 256, 6), 256, 0, stream>>>(wa);

  // CSR by dst
  hist_kernel<<<eb, 256, 0, stream>>>(dst, cursor, E);
  block_reduce<<<nb, 256, 0, stream>>>(cursor, partial, N);
  scan_partials<<<1, 256, 0, stream>>>(partial, nb, rowptr + N);
  block_scan<<<nb, 256, 0, stream>>>(cursor, partial, rowptr, N);
  build_kernel<<<eb, 256, 0, stream>>>(src, dst, cursor, srcList, E);

  // ---- layer 1 (K padded 33 -> 64) ----
  gather_x<<<N, 64, 0, stream>>>(x, rowptr, srcList, A, N);
  gin_mlp<64, true><<<256, 512, 0, stream>>>(
      A, Wt[0], Wt[1], b1[0], gm[0], be[0], mu[0], vr[0], b2[0],
      P, batch, pools, tick + 0, N);

  // ---- layer 2 ----
  gather_h<<<N, 64, 0, stream>>>(P, rowptr, srcList, A, N);
  gin_mlp<128, true><<<256, 512, 0, stream>>>(
      A, Wt[2], Wt[3], b1[1], gm[1], be[1], mu[1], vr[1], b2[1],
      P, batch, pools + GG * H, tick + 1, N);

  // ---- layer 3 (h3 pooled only) ----
  gather_h<<<N, 64, 0, stream>>>(P, rowptr, srcList, A, N);
  gin_mlp<128, false><<<256, 512, 0, stream>>>(
      A, Wt[4], Wt[5], b1[2], gm[2], be[2], mu[2], vr[2], b2[2],
      nullptr, batch, pools + 2 * GG * H, tick + 2, N);

  // ---- head ----
  head_kernel<<<GG, 64, 0, stream>>>(pools, l1w, l1b, l2w, l2b, l3w, l3b, (float*)d_out);
}